// Round 2
// baseline (21050.438 us; speedup 1.0000x reference)
//
#include <hip/hip_runtime.h>
#include <stdint.h>
#include <math.h>

// Seq2seq LSTM, round-5 design.
// rnn_kernel: 64 WGs x 512 threads. Each WG owns 16 hidden units = exactly one
// private 64B line per slot: single-producer, full-line, one predicated 16-lane
// store per publish (no false sharing -- round-4's packed multi-producer lines
// caused 8x write amplification and regressed). Consumers read the packed slot
// (64 lines / 4KB, contiguous): 256 pollers x 16B, fully coalesced. Poll
// fan-in: 64 WGs x 64 lines = 4096 line-requests/round (16x less than round-3,
// 4x less than round-4). Wave w (8 waves) computes units wg*16+w and wg*16+8+w:
// flat w[48] float4 weight array (round-3's proven register-promotion shape,
// ~225 VGPR, 2 waves/SIMD). Cells per-wave, h collected via LDS, published by
// wave 0. Slot protocol identical to the verified rounds: 4-slot rotation,
// sentinel 0x7F7F7F7F, clear own line in slot (t+2)&3 post-gather (wave 0),
// drained by wave-0 vmcnt(0) before the publish of h_{t+1}.
//
// ws: [0]      hbuf: 4 slots x 1024 dwords = 16 KB (memset 0x7F)
//     [65536]  Adec: T x 1024 bf16 decoder hidden states (1 MB)

typedef __attribute__((ext_vector_type(8))) short short8;
typedef __attribute__((ext_vector_type(4))) float f32x4;
typedef unsigned long long u64;

#define HD 1024
#define ED 512
#define TPB 256          // out_gemm / softmax block size
#define RNN_TPB 512
#define RNN_NWG 64
#define SENT32 0x7F7F7F7Fu

#define AGT __HIP_MEMORY_SCOPE_AGENT
#define RLX __ATOMIC_RELAXED

__device__ __forceinline__ unsigned short f2bf(float f) {
  union { float f; unsigned u; } x; x.f = f;
  unsigned u = x.u;
  u += 0x7fffu + ((u >> 16) & 1u);        // RNE
  return (unsigned short)(u >> 16);
}
__device__ __forceinline__ float frcp(float x) { return __builtin_amdgcn_rcpf(x); }
__device__ __forceinline__ float fsig(float x) { return frcp(1.0f + __expf(-x)); }
__device__ __forceinline__ float ftanh(float x) { return 1.0f - 2.0f * frcp(1.0f + __expf(2.0f * x)); }

#define DOT4(a, W, v) \
  a = fmaf((W).x, (v).x, fmaf((W).y, (v).y, fmaf((W).z, (v).z, fmaf((W).w, (v).w, (a)))))

__global__ __launch_bounds__(RNN_TPB)
void rnn_kernel(const int* __restrict__ state,
                const float* __restrict__ emb,
                const float* __restrict__ encWih,
                const float* __restrict__ encWhh,
                const float* __restrict__ encbih,
                const float* __restrict__ encbhh,
                const float* __restrict__ decWhh,
                const float* __restrict__ decbih,
                const float* __restrict__ decbhh,
                unsigned int* __restrict__ hbuf,   // [4][1024] dwords (float payload)
                unsigned short* __restrict__ Adec, // [T][1024] bf16
                int S, int T) {
  __shared__ __align__(16) float vec[HD + ED];     // [h(1024) | x(512)]
  __shared__ float gsh[16];

  const int tid = threadIdx.x;
  const int wg  = blockIdx.x;
  const int wv  = tid >> 6;          // wave 0..7
  const int c   = tid & 63;
  const int uA  = (wg << 4) + wv;    // unit A (this wave)
  const int uB  = uA + 8;            // unit B

  // ---- weights in registers: flat float4 array, constant-indexed ----
  // w[a*16 + g*4 + j]  (j=0..3): Whh row (g*HD+u), h-chunk 16B
  // w[32 + a*8 + g*2 + j] (j=0..1): Wih row, x-chunk 16B
  float4 w[48];
#pragma unroll
  for (int g = 0; g < 4; ++g) {
#pragma unroll
    for (int j = 0; j < 4; ++j) {
      w[g * 4 + j]      = *(const float4*)&encWhh[((size_t)(g * HD) + uA) * HD + 4 * (c + 64 * j)];
      w[16 + g * 4 + j] = *(const float4*)&encWhh[((size_t)(g * HD) + uB) * HD + 4 * (c + 64 * j)];
    }
#pragma unroll
    for (int j = 0; j < 2; ++j) {
      w[32 + g * 2 + j] = *(const float4*)&encWih[((size_t)(g * HD) + uA) * ED + 4 * (c + 64 * j)];
      w[40 + g * 2 + j] = *(const float4*)&encWih[((size_t)(g * HD) + uB) * ED + 4 * (c + 64 * j)];
    }
  }
  float4 brA, brB;
  brA.x = encbih[0 * HD + uA] + encbhh[0 * HD + uA];
  brA.y = encbih[1 * HD + uA] + encbhh[1 * HD + uA];
  brA.z = encbih[2 * HD + uA] + encbhh[2 * HD + uA];
  brA.w = encbih[3 * HD + uA] + encbhh[3 * HD + uA];
  brB.x = encbih[0 * HD + uB] + encbhh[0 * HD + uB];
  brB.y = encbih[1 * HD + uB] + encbhh[1 * HD + uB];
  brB.z = encbih[2 * HD + uB] + encbhh[2 * HD + uB];
  brB.w = encbih[3 * HD + uB] + encbhh[3 * HD + uB];

  float csA = 0.0f, csB = 0.0f;      // cell states (replicated across lanes)

  for (int t = 0; t < S + T; ++t) {
    const bool dec = (t >= S);
    if (t == S) {                    // one-time decoder weight switch
#pragma unroll
      for (int g = 0; g < 4; ++g)
#pragma unroll
        for (int j = 0; j < 4; ++j) {
          w[g * 4 + j]      = *(const float4*)&decWhh[((size_t)(g * HD) + uA) * HD + 4 * (c + 64 * j)];
          w[16 + g * 4 + j] = *(const float4*)&decWhh[((size_t)(g * HD) + uB) * HD + 4 * (c + 64 * j)];
        }
      brA.x = decbih[0 * HD + uA] + decbhh[0 * HD + uA];
      brA.y = decbih[1 * HD + uA] + decbhh[1 * HD + uA];
      brA.z = decbih[2 * HD + uA] + decbhh[2 * HD + uA];
      brA.w = decbih[3 * HD + uA] + decbhh[3 * HD + uA];
      brB.x = decbih[0 * HD + uB] + decbhh[0 * HD + uB];
      brB.y = decbih[1 * HD + uB] + decbhh[1 * HD + uB];
      brB.z = decbih[2 * HD + uB] + decbhh[2 * HD + uB];
      brB.w = decbih[3 * HD + uB] + decbhh[3 * HD + uB];
    }

    // ---- gather: pollers (tid<256) pull 16B each from the packed slot ----
    if (tid < 256) {
      if (t == 0) {
        *(float4*)&vec[4 * tid] = make_float4(0.f, 0.f, 0.f, 0.f);
      } else {
        const u64* L = (const u64*)hbuf + (((size_t)(t & 3)) << 9) + (tid << 1);
        u64 d0, d1;
        do {
          d0 = __hip_atomic_load(&L[0], RLX, AGT);
          d1 = __hip_atomic_load(&L[1], RLX, AGT);
        } while ((unsigned)d0 == SENT32 || (unsigned)(d0 >> 32) == SENT32 ||
                 (unsigned)d1 == SENT32 || (unsigned)(d1 >> 32) == SENT32);
        union { u64 u[2]; float4 f; } p;
        p.u[0] = d0; p.u[1] = d1;
        *(float4*)&vec[4 * tid] = p.f;
      }
    } else if (tid < 384) {
      if (!dec) {                    // stage x_t = emb[state[t]]
        int tok = state[t];
        *(float4*)&vec[HD + 4 * (tid - 256)] =
            *(const float4*)&emb[(size_t)tok * ED + 4 * (tid - 256)];
      }
    }
    __syncthreads();

    // ---- re-sentinel own line in slot (t+2)&3 (wave 0, one 64B store) ----
    // Safe: we gathered h_t => every WG finished reading slot (t+2)&3 (it held
    // h_{t-2}). Drained by the vmcnt(0) below before publishing h_{t+1}.
    if (tid < 16)
      __hip_atomic_store(&hbuf[(size_t)((t + 2) & 3) * HD + (wg << 4) + tid], SENT32, RLX, AGT);

    // ---- dot: 8 gate rows (2 units x 4 gates) share each vec chunk ----
    float acc[8] = {0.f, 0.f, 0.f, 0.f, 0.f, 0.f, 0.f, 0.f};
#pragma unroll
    for (int j = 0; j < 4; ++j) {
      float4 v = *(const float4*)&vec[4 * (c + 64 * j)];
#pragma unroll
      for (int g = 0; g < 4; ++g) {
        DOT4(acc[g],     w[g * 4 + j],      v);
        DOT4(acc[4 + g], w[16 + g * 4 + j], v);
      }
    }
    if (!dec) {
#pragma unroll
      for (int j = 0; j < 2; ++j) {
        float4 v = *(const float4*)&vec[HD + 4 * (c + 64 * j)];
#pragma unroll
        for (int g = 0; g < 4; ++g) {
          DOT4(acc[g],     w[32 + g * 2 + j], v);
          DOT4(acc[4 + g], w[40 + g * 2 + j], v);
        }
      }
    }
    // in-wave butterfly reduce (all lanes end with full sums)
#pragma unroll
    for (int off = 1; off < 64; off <<= 1)
#pragma unroll
      for (int q = 0; q < 8; ++q)
        acc[q] += __shfl_xor(acc[q], off);

    // ---- LSTM cells (replicated across the wave, no divergence) ----
    float iA = fsig(acc[0] + brA.x), fA = fsig(acc[1] + brA.y);
    float gA = ftanh(acc[2] + brA.z), oA = fsig(acc[3] + brA.w);
    csA = fA * csA + iA * gA;
    float hA = oA * ftanh(csA);
    float iB = fsig(acc[4] + brB.x), fB = fsig(acc[5] + brB.y);
    float gB = ftanh(acc[6] + brB.z), oB = fsig(acc[7] + brB.w);
    csB = fB * csB + iB * gB;
    float hB = oB * ftanh(csB);

    if (c == 0) { gsh[wv] = hA; gsh[wv + 8] = hB; }
    __syncthreads();                 // also protects vec for next gather

    // ---- publish: wave 0 lanes 0..15, one coalesced 64B line store ----
    if (tid < 16) {
      float hv = gsh[tid];
      // drain the sentinel-clear (wave-0 stores) before publishing
      asm volatile("s_waitcnt vmcnt(0)" ::: "memory");
      union { float f; unsigned u; } x; x.f = hv;
      __hip_atomic_store(&hbuf[(size_t)((t + 1) & 3) * HD + (wg << 4) + tid], x.u, RLX, AGT);
      if (dec) Adec[(size_t)(t - S) * HD + (wg << 4) + tid] = f2bf(hv);
    }
  }
}

// ---- output head GEMM: out[t][v] = Adec[t] . Wout[v] + bout[v] ----
// WG tile: 512 t x 64 v. Wave w: t in [w*128, w*128+128), v in [v0, v0+64).
// Per k-step (K=32): stage A-slice (512x32 bf16, padded stride) in LDS,
// 8 a-frags + 4 b-frags -> 32 MFMA per wave. Wout (206 MB) read exactly once.
#define AST 56   // Alds row stride in ushorts

__global__ __launch_bounds__(TPB)
void out_gemm(const unsigned short* __restrict__ Adec,
              const float* __restrict__ Wout,
              const float* __restrict__ bout,
              float* __restrict__ out,
              int V) {
  __shared__ __align__(16) unsigned short Alds[512 * AST]; // 56 KB
  const int tid  = threadIdx.x;
  const int wv   = tid >> 6;
  const int lane = tid & 63;
  const int col  = lane & 15;
  const int quad = lane >> 4;
  const int v0   = blockIdx.x * 64;

  f32x4 acc[4][8];
#pragma unroll
  for (int bt = 0; bt < 4; ++bt)
#pragma unroll
    for (int tt = 0; tt < 8; ++tt)
      acc[bt][tt] = (f32x4){0.f, 0.f, 0.f, 0.f};

  for (int k0 = 0; k0 < HD; k0 += 32) {
    __syncthreads();
    // stage A k-slice: 512 rows x 32 bf16 (4 x uint4 chunks per row)
#pragma unroll
    for (int i = 0; i < 8; ++i) {
      int id = tid + (i << 8);             // 0..2047
      int rt = id >> 2, c4 = id & 3;
      uint4 d = *(const uint4*)(Adec + rt * HD + k0 + (c4 << 3));
      *(uint4*)&Alds[rt * AST + (c4 << 3)] = d;
    }
    __syncthreads();
    // B fragments from global (fp32 -> bf16): lane l covers Wout[v0+bt*16+col][k0+quad*8 ..+7]
    short8 bf[4];
#pragma unroll
    for (int bt = 0; bt < 4; ++bt) {
      int v = v0 + (bt << 4) + col;
      if (v >= V) v = V - 1;
      const float4* wp = (const float4*)(Wout + (size_t)v * HD + k0 + (quad << 3));
      float4 w0 = wp[0], w1 = wp[1];
      short8 b;
      b[0] = (short)f2bf(w0.x); b[1] = (short)f2bf(w0.y);
      b[2] = (short)f2bf(w0.z); b[3] = (short)f2bf(w0.w);
      b[4] = (short)f2bf(w1.x); b[5] = (short)f2bf(w1.y);
      b[6] = (short)f2bf(w1.z); b[7] = (short)f2bf(w1.w);
      bf[bt] = b;
    }
#pragma unroll
    for (int tt = 0; tt < 8; ++tt) {
      int trow = (wv << 7) + (tt << 4) + col;
      short8 af = *(const short8*)&Alds[trow * AST + (quad << 3)];
#pragma unroll
      for (int bt = 0; bt < 4; ++bt)
        acc[bt][tt] = __builtin_amdgcn_mfma_f32_16x16x32_bf16(af, bf[bt], acc[bt][tt], 0, 0, 0);
    }
  }
  // epilogue: C/D layout col = lane&15 (v), row = quad*4 + reg (t)
#pragma unroll
  for (int bt = 0; bt < 4; ++bt) {
    int v = v0 + (bt << 4) + col;
    if (v < V) {
      float bb = bout[v];
#pragma unroll
      for (int tt = 0; tt < 8; ++tt) {
        int tb = (wv << 7) + (tt << 4) + (quad << 2);
        f32x4 a = acc[bt][tt];
        out[(size_t)(tb + 0) * V + v] = a[0] + bb;
        out[(size_t)(tb + 1) * V + v] = a[1] + bb;
        out[(size_t)(tb + 2) * V + v] = a[2] + bb;
        out[(size_t)(tb + 3) * V + v] = a[3] + bb;
      }
    }
  }
}

// ---- row softmax in place over d_out: one WG per t ----
__global__ __launch_bounds__(TPB)
void softmax_rows(float* __restrict__ out, int V) {
  float* rowp = out + (size_t)blockIdx.x * V;
  __shared__ float red[8];
  const int tid = threadIdx.x;

  float m = -1e30f;
  for (int v = tid; v < V; v += TPB) m = fmaxf(m, rowp[v]);
#pragma unroll
  for (int off = 32; off >= 1; off >>= 1) m = fmaxf(m, __shfl_xor(m, off));
  if ((tid & 63) == 0) red[tid >> 6] = m;
  __syncthreads();
  if (tid == 0) red[4] = fmaxf(fmaxf(red[0], red[1]), fmaxf(red[2], red[3]));
  __syncthreads();
  m = red[4];

  float s = 0.0f;
  for (int v = tid; v < V; v += TPB) {
    float e = expf(rowp[v] - m);
    rowp[v] = e;
    s += e;
  }
#pragma unroll
  for (int off = 32; off >= 1; off >>= 1) s += __shfl_xor(s, off);
  if ((tid & 63) == 0) red[tid >> 6] = s;
  __syncthreads();
  if (tid == 0) red[5] = red[0] + red[1] + red[2] + red[3];
  __syncthreads();
  float inv = 1.0f / red[5];
  for (int v = tid; v < V; v += TPB) rowp[v] *= inv;
}

extern "C" void kernel_launch(void* const* d_in, const int* in_sizes, int n_in,
                              void* d_out, int out_size, void* d_ws, size_t ws_size,
                              hipStream_t stream) {
  const int*   state  = (const int*)d_in[0];
  // d_in[1] = max_len scalar (T derived from out_size instead)
  const float* emb    = (const float*)d_in[2];
  const float* encWih = (const float*)d_in[3];
  const float* encWhh = (const float*)d_in[4];
  const float* encbih = (const float*)d_in[5];
  const float* encbhh = (const float*)d_in[6];
  // d_in[7] = dec_Wih (multiplied by zero input in reference -> unused)
  const float* decWhh = (const float*)d_in[8];
  const float* decbih = (const float*)d_in[9];
  const float* decbhh = (const float*)d_in[10];
  const float* Wout   = (const float*)d_in[11];
  const float* bout   = (const float*)d_in[12];
  float*       out    = (float*)d_out;

  const int S = in_sizes[0];          // 2048
  const int V = in_sizes[12];         // 50257
  const int T = out_size / V;         // 512

  // sentinel-fill the packed h slots (0x7F byte pattern)
  hipMemsetAsync(d_ws, 0x7F, 16384, stream);
  unsigned int*   hbuf = (unsigned int*)d_ws;
  unsigned short* Adec = (unsigned short*)((char*)d_ws + 65536);

  rnn_kernel<<<RNN_NWG, RNN_TPB, 0, stream>>>(state, emb, encWih, encWhh, encbih, encbhh,
                                              decWhh, decbih, decbhh, hbuf, Adec, S, T);
  int nvb = (V + 63) / 64;
  out_gemm<<<nvb, TPB, 0, stream>>>(Adec, Wout, bout, out, V);
  softmax_rows<<<T, TPB, 0, stream>>>(out, V);
}

// Round 3
// 10749.641 us; speedup vs baseline: 1.9582x; 1.9582x over previous
//
#include <hip/hip_runtime.h>
#include <stdint.h>
#include <math.h>

// Seq2seq LSTM, round-6 design.
// rnn_kernel: 256 WGs x 256 threads (round-3's proven spill-free compute shape:
// flat float4 w[24] = 96 VGPRs/thread, ~120 total, 1 WG/CU, dot ~200cy).
// Changes vs round 3 (each targeted at the ~7000cy/step overhead):
//  - hbuf is a PACKED 4KB slot (4-slot rotation): WG wg owns dwords 4wg..4wg+3.
//    Pollers read 16B contiguous each -> 64 lines/WG/round, 4x less poll
//    fan-in than round-3's 256 scattered private lines (r4/r5 proved the
//    FETCH reduction).
//  - Per-wave de-skewed publish: wave u owns unit wg*4+u end-to-end (dot rows
//    4u..4u+3, in-wave reduce, replicated cell, lane-0 dword publish) -- no
//    gsh collect, no wave-0 serialization, publish issues the moment each
//    unit's cell is done.
//  - vec is double-buffered -> exactly ONE __syncthreads per step (r3 had 2);
//    waves that finish early start polling t+1 while siblings compute.
// Sentinel protocol identical to the verified rounds: 4-slot rotation,
// 0x7F7F7F7F sentinel, each wave's lane 0 re-sentinels ITS OWN dword in slot
// (t+2)&3 right after the gather barrier (transitive-gather proof makes it
// safe), drained by the SAME thread's vmcnt(0) before it publishes h_{t+2}
// into that slot at step t+1.
//
// ws: [0]      hbuf: 4 slots x 1024 dwords = 16 KB (memset 0x7F)
//     [65536]  Adec: T x 1024 bf16 decoder hidden states (1 MB)

typedef __attribute__((ext_vector_type(8))) short short8;
typedef __attribute__((ext_vector_type(4))) float f32x4;
typedef unsigned long long u64;

#define HD 1024
#define ED 512
#define TPB 256
#define NWG 256
#define SENT32 0x7F7F7F7Fu

#define AGT __HIP_MEMORY_SCOPE_AGENT
#define RLX __ATOMIC_RELAXED

__device__ __forceinline__ unsigned short f2bf(float f) {
  union { float f; unsigned u; } x; x.f = f;
  unsigned u = x.u;
  u += 0x7fffu + ((u >> 16) & 1u);        // RNE
  return (unsigned short)(u >> 16);
}
__device__ __forceinline__ float frcp(float x) { return __builtin_amdgcn_rcpf(x); }
__device__ __forceinline__ float fsig(float x) { return frcp(1.0f + __expf(-x)); }
__device__ __forceinline__ float ftanh(float x) { return 1.0f - 2.0f * frcp(1.0f + __expf(2.0f * x)); }

__global__ __launch_bounds__(TPB)
void rnn_kernel(const int* __restrict__ state,
                const float* __restrict__ emb,
                const float* __restrict__ encWih,
                const float* __restrict__ encWhh,
                const float* __restrict__ encbih,
                const float* __restrict__ encbhh,
                const float* __restrict__ decWhh,
                const float* __restrict__ decbih,
                const float* __restrict__ decbhh,
                unsigned int* __restrict__ hbuf,   // [4][1024] dwords (float payload)
                unsigned short* __restrict__ Adec, // [T][1024] bf16
                int S, int T) {
  __shared__ __align__(16) float vec[2][HD + ED];  // double-buffered [h|x]

  const int tid  = threadIdx.x;
  const int wg   = blockIdx.x;
  const int row  = tid >> 4;           // gate row 0..15
  const int c    = tid & 15;           // 16 lanes per row
  const int u    = tid >> 6;           // wave id == local unit 0..3
  const int lane = tid & 63;
  // LDS row r <-> global gate row: gate = r&3 (i,f,g,o), unit = r>>2 (== wave)
  const int grow = (row & 3) * HD + (wg << 2) + (row >> 2);
  const int gu   = (wg << 2) + u;      // global unit of this wave

  // ---- weights in registers: 24 x float4 = 96 fp32 VGPRs (proven shape) ----
  float4 w[24];
#pragma unroll
  for (int j = 0; j < 16; ++j)
    w[j] = *(const float4*)&encWhh[(size_t)grow * HD + 4 * (c + 16 * j)];
#pragma unroll
  for (int j = 16; j < 24; ++j)
    w[j] = *(const float4*)&encWih[(size_t)grow * ED + 4 * (c + 16 * j) - HD];
  float breg = encbih[grow] + encbhh[grow];

  float cs = 0.0f;                     // cell state (replicated across wave)

  for (int t = 0; t < S + T; ++t) {
    const bool dec = (t >= S);
    if (t == S) {                      // one-time decoder weight switch
#pragma unroll
      for (int j = 0; j < 16; ++j)
        w[j] = *(const float4*)&decWhh[(size_t)grow * HD + 4 * (c + 16 * j)];
      breg = decbih[grow] + decbhh[grow];
    }

    float* vb = vec[t & 1];

    // ---- gather h_t (and x_t for encoder) into vb ----
    if (t == 0) {
      *(float4*)&vb[4 * tid] = make_float4(0.f, 0.f, 0.f, 0.f);
      if (tid >= 128) {
        int tok = state[0];
        *(float4*)&vb[HD + 4 * (tid - 128)] =
            *(const float4*)&emb[(size_t)tok * ED + 4 * (tid - 128)];
      }
    } else {
      float4 xv;
      const bool havex = (!dec) && (tid >= 128);
      if (havex) {                     // issue emb load BEFORE the poll
        int tok = state[t];
        xv = *(const float4*)&emb[(size_t)tok * ED + 4 * (tid - 128)];
      }
      // packed slot: thread reads its 16B (dwords 4*tid..4*tid+3), coalesced
      const u64* L = (const u64*)hbuf + (((size_t)(t & 3)) << 9) + (tid << 1);
      u64 d0, d1;
      do {
        d0 = __hip_atomic_load(&L[0], RLX, AGT);
        d1 = __hip_atomic_load(&L[1], RLX, AGT);
      } while ((unsigned)d0 == SENT32 || (unsigned)(d0 >> 32) == SENT32 ||
               (unsigned)d1 == SENT32 || (unsigned)(d1 >> 32) == SENT32);
      union { u64 u[2]; float4 f; } p;
      p.u[0] = d0; p.u[1] = d1;
      *(float4*)&vb[4 * tid] = p.f;
      if (havex) *(float4*)&vb[HD + 4 * (tid - 128)] = xv;
    }
    __syncthreads();                   // the ONLY barrier per step

    // ---- re-sentinel own dword in slot (t+2)&3 (lane 0 of each wave) ----
    // Safe: gather of h_t completed => every WG finished reading slot
    // (t+2)&3 (it held h_{t-2}). Drained by THIS thread's vmcnt(0) before
    // it publishes h_{t+2} into the same dword at step t+1.
    if (lane == 0)
      __hip_atomic_store(&hbuf[(size_t)((t + 2) & 3) * HD + gu], SENT32, RLX, AGT);

    // ---- dot: row x vb, 4-float chunks at canonical 16B lane stride ----
    float a0 = (c == 0) ? breg : 0.0f, a1 = 0.f, a2 = 0.f, a3 = 0.f;
    if (!dec) {
#pragma unroll
      for (int j = 0; j < 24; j += 4) {
        float4 v0 = *(const float4*)&vb[4 * (c + 16 * (j + 0))];
        float4 v1 = *(const float4*)&vb[4 * (c + 16 * (j + 1))];
        float4 v2 = *(const float4*)&vb[4 * (c + 16 * (j + 2))];
        float4 v3 = *(const float4*)&vb[4 * (c + 16 * (j + 3))];
        float4 w0 = w[j + 0], w1 = w[j + 1], w2 = w[j + 2], w3 = w[j + 3];
        a0 = fmaf(w0.x, v0.x, fmaf(w0.y, v0.y, fmaf(w0.z, v0.z, fmaf(w0.w, v0.w, a0))));
        a1 = fmaf(w1.x, v1.x, fmaf(w1.y, v1.y, fmaf(w1.z, v1.z, fmaf(w1.w, v1.w, a1))));
        a2 = fmaf(w2.x, v2.x, fmaf(w2.y, v2.y, fmaf(w2.z, v2.z, fmaf(w2.w, v2.w, a2))));
        a3 = fmaf(w3.x, v3.x, fmaf(w3.y, v3.y, fmaf(w3.z, v3.z, fmaf(w3.w, v3.w, a3))));
      }
    } else {
#pragma unroll
      for (int j = 0; j < 16; j += 4) {
        float4 v0 = *(const float4*)&vb[4 * (c + 16 * (j + 0))];
        float4 v1 = *(const float4*)&vb[4 * (c + 16 * (j + 1))];
        float4 v2 = *(const float4*)&vb[4 * (c + 16 * (j + 2))];
        float4 v3 = *(const float4*)&vb[4 * (c + 16 * (j + 3))];
        float4 w0 = w[j + 0], w1 = w[j + 1], w2 = w[j + 2], w3 = w[j + 3];
        a0 = fmaf(w0.x, v0.x, fmaf(w0.y, v0.y, fmaf(w0.z, v0.z, fmaf(w0.w, v0.w, a0))));
        a1 = fmaf(w1.x, v1.x, fmaf(w1.y, v1.y, fmaf(w1.z, v1.z, fmaf(w1.w, v1.w, a1))));
        a2 = fmaf(w2.x, v2.x, fmaf(w2.y, v2.y, fmaf(w2.z, v2.z, fmaf(w2.w, v2.w, a2))));
        a3 = fmaf(w3.x, v3.x, fmaf(w3.y, v3.y, fmaf(w3.z, v3.z, fmaf(w3.w, v3.w, a3))));
      }
    }
    float acc = (a0 + a1) + (a2 + a3);
    // reduce within each 16-lane row group
    acc += __shfl_xor(acc, 1);
    acc += __shfl_xor(acc, 2);
    acc += __shfl_xor(acc, 4);
    acc += __shfl_xor(acc, 8);

    // ---- per-wave LSTM cell (replicated, no divergence): row sums of gates
    // i,f,g,o sit in lanes 0,16,32,48 of this wave ----
    float gi = __shfl(acc, 0);
    float gf = __shfl(acc, 16);
    float gg = __shfl(acc, 32);
    float go = __shfl(acc, 48);
    float iv = fsig(gi), fv = fsig(gf), gv = ftanh(gg), ov = fsig(go);
    cs = fv * cs + iv * gv;
    float hv = ov * ftanh(cs);

    // ---- publish: lane 0 of each wave stores its unit's dword ----
    if (lane == 0) {
      // drain this thread's prior sentinel-clear of the target slot
      asm volatile("s_waitcnt vmcnt(0)" ::: "memory");
      union { float f; unsigned u; } x; x.f = hv;
      __hip_atomic_store(&hbuf[(size_t)((t + 1) & 3) * HD + gu], x.u, RLX, AGT);
      if (dec) Adec[(size_t)(t - S) * HD + gu] = f2bf(hv);
    }
  }
}

// ---- output head GEMM: out[t][v] = Adec[t] . Wout[v] + bout[v] ----
// WG tile: 512 t x 64 v. Wave w: t in [w*128, w*128+128), v in [v0, v0+64).
// Per k-step (K=32): stage A-slice (512x32 bf16, padded stride) in LDS,
// 8 a-frags + 4 b-frags -> 32 MFMA per wave. Wout (206 MB) read exactly once.
#define AST 56   // Alds row stride in ushorts

__global__ __launch_bounds__(TPB)
void out_gemm(const unsigned short* __restrict__ Adec,
              const float* __restrict__ Wout,
              const float* __restrict__ bout,
              float* __restrict__ out,
              int V) {
  __shared__ __align__(16) unsigned short Alds[512 * AST]; // 56 KB
  const int tid  = threadIdx.x;
  const int wv   = tid >> 6;
  const int lane = tid & 63;
  const int col  = lane & 15;
  const int quad = lane >> 4;
  const int v0   = blockIdx.x * 64;

  f32x4 acc[4][8];
#pragma unroll
  for (int bt = 0; bt < 4; ++bt)
#pragma unroll
    for (int tt = 0; tt < 8; ++tt)
      acc[bt][tt] = (f32x4){0.f, 0.f, 0.f, 0.f};

  for (int k0 = 0; k0 < HD; k0 += 32) {
    __syncthreads();
    // stage A k-slice: 512 rows x 32 bf16 (4 x uint4 chunks per row)
#pragma unroll
    for (int i = 0; i < 8; ++i) {
      int id = tid + (i << 8);             // 0..2047
      int rt = id >> 2, c4 = id & 3;
      uint4 d = *(const uint4*)(Adec + rt * HD + k0 + (c4 << 3));
      *(uint4*)&Alds[rt * AST + (c4 << 3)] = d;
    }
    __syncthreads();
    // B fragments from global (fp32 -> bf16): lane l covers Wout[v0+bt*16+col][k0+quad*8 ..+7]
    short8 bf[4];
#pragma unroll
    for (int bt = 0; bt < 4; ++bt) {
      int v = v0 + (bt << 4) + col;
      if (v >= V) v = V - 1;
      const float4* wp = (const float4*)(Wout + (size_t)v * HD + k0 + (quad << 3));
      float4 w0 = wp[0], w1 = wp[1];
      short8 b;
      b[0] = (short)f2bf(w0.x); b[1] = (short)f2bf(w0.y);
      b[2] = (short)f2bf(w0.z); b[3] = (short)f2bf(w0.w);
      b[4] = (short)f2bf(w1.x); b[5] = (short)f2bf(w1.y);
      b[6] = (short)f2bf(w1.z); b[7] = (short)f2bf(w1.w);
      bf[bt] = b;
    }
#pragma unroll
    for (int tt = 0; tt < 8; ++tt) {
      int trow = (wv << 7) + (tt << 4) + col;
      short8 af = *(const short8*)&Alds[trow * AST + (quad << 3)];
#pragma unroll
      for (int bt = 0; bt < 4; ++bt)
        acc[bt][tt] = __builtin_amdgcn_mfma_f32_16x16x32_bf16(af, bf[bt], acc[bt][tt], 0, 0, 0);
    }
  }
  // epilogue: C/D layout col = lane&15 (v), row = quad*4 + reg (t)
#pragma unroll
  for (int bt = 0; bt < 4; ++bt) {
    int v = v0 + (bt << 4) + col;
    if (v < V) {
      float bb = bout[v];
#pragma unroll
      for (int tt = 0; tt < 8; ++tt) {
        int tb = (wv << 7) + (tt << 4) + (quad << 2);
        f32x4 a = acc[bt][tt];
        out[(size_t)(tb + 0) * V + v] = a[0] + bb;
        out[(size_t)(tb + 1) * V + v] = a[1] + bb;
        out[(size_t)(tb + 2) * V + v] = a[2] + bb;
        out[(size_t)(tb + 3) * V + v] = a[3] + bb;
      }
    }
  }
}

// ---- row softmax in place over d_out: one WG per t ----
__global__ __launch_bounds__(TPB)
void softmax_rows(float* __restrict__ out, int V) {
  float* rowp = out + (size_t)blockIdx.x * V;
  __shared__ float red[8];
  const int tid = threadIdx.x;

  float m = -1e30f;
  for (int v = tid; v < V; v += TPB) m = fmaxf(m, rowp[v]);
#pragma unroll
  for (int off = 32; off >= 1; off >>= 1) m = fmaxf(m, __shfl_xor(m, off));
  if ((tid & 63) == 0) red[tid >> 6] = m;
  __syncthreads();
  if (tid == 0) red[4] = fmaxf(fmaxf(red[0], red[1]), fmaxf(red[2], red[3]));
  __syncthreads();
  m = red[4];

  float s = 0.0f;
  for (int v = tid; v < V; v += TPB) {
    float e = expf(rowp[v] - m);
    rowp[v] = e;
    s += e;
  }
#pragma unroll
  for (int off = 32; off >= 1; off >>= 1) s += __shfl_xor(s, off);
  if ((tid & 63) == 0) red[tid >> 6] = s;
  __syncthreads();
  if (tid == 0) red[5] = red[0] + red[1] + red[2] + red[3];
  __syncthreads();
  float inv = 1.0f / red[5];
  for (int v = tid; v < V; v += TPB) rowp[v] *= inv;
}

extern "C" void kernel_launch(void* const* d_in, const int* in_sizes, int n_in,
                              void* d_out, int out_size, void* d_ws, size_t ws_size,
                              hipStream_t stream) {
  const int*   state  = (const int*)d_in[0];
  // d_in[1] = max_len scalar (T derived from out_size instead)
  const float* emb    = (const float*)d_in[2];
  const float* encWih = (const float*)d_in[3];
  const float* encWhh = (const float*)d_in[4];
  const float* encbih = (const float*)d_in[5];
  const float* encbhh = (const float*)d_in[6];
  // d_in[7] = dec_Wih (multiplied by zero input in reference -> unused)
  const float* decWhh = (const float*)d_in[8];
  const float* decbih = (const float*)d_in[9];
  const float* decbhh = (const float*)d_in[10];
  const float* Wout   = (const float*)d_in[11];
  const float* bout   = (const float*)d_in[12];
  float*       out    = (float*)d_out;

  const int S = in_sizes[0];          // 2048
  const int V = in_sizes[12];         // 50257
  const int T = out_size / V;         // 512

  // sentinel-fill the packed h slots (0x7F byte pattern)
  hipMemsetAsync(d_ws, 0x7F, 16384, stream);
  unsigned int*   hbuf = (unsigned int*)d_ws;
  unsigned short* Adec = (unsigned short*)((char*)d_ws + 65536);

  rnn_kernel<<<NWG, TPB, 0, stream>>>(state, emb, encWih, encWhh, encbih, encbhh,
                                      decWhh, decbih, decbhh, hbuf, Adec, S, T);
  int nvb = (V + 63) / 64;
  out_gemm<<<nvb, TPB, 0, stream>>>(Adec, Wout, bout, out, V);
  softmax_rows<<<T, TPB, 0, stream>>>(out, V);
}